// Round 1
// baseline (471.167 us; speedup 1.0000x reference)
//
#include <hip/hip_runtime.h>

#define HID 512
#define POOL 4096
#define N_OBJ 1280
#define N_REL 16384
#define NOC 151
#define NRC 51
#define KSPLIT 8

typedef _Float16 half_t;
typedef half_t h16x8 __attribute__((ext_vector_type(8)));
typedef float f32x4 __attribute__((ext_vector_type(4)));

// LDS row stride for 64-k f16 tiles: 72 elems = 144 B. Both b128 reads and
// writes spread uniformly over the 8 four-bank groups (bandwidth-optimal).
#define LDSTR 72

// ---------------------------------------------------------------------------
// device helper: transpose+downconvert one 64x64 tile.
// src: K x N fp32 (n-fast) -> dst: N x K f16 (k-fast)
// ---------------------------------------------------------------------------
__device__ __forceinline__ void kt_tile(
    const float* __restrict__ src, half_t* __restrict__ dst,
    int K, int N, int kb, int nb, half_t* Ts)
{
    const int t = threadIdx.x;
    const int kr = t >> 4;
    const int nc = (t & 15) * 4;
#pragma unroll
    for (int p = 0; p < 4; ++p) {
        float4 v = *(const float4*)(src + (size_t)(kb + kr + 16 * p) * N + nb + nc);
        Ts[(nc + 0) * LDSTR + kr + 16 * p] = (half_t)v.x;
        Ts[(nc + 1) * LDSTR + kr + 16 * p] = (half_t)v.y;
        Ts[(nc + 2) * LDSTR + kr + 16 * p] = (half_t)v.z;
        Ts[(nc + 3) * LDSTR + kr + 16 * p] = (half_t)v.w;
    }
    __syncthreads();
    const int n = t >> 2, kk = (t & 3) * 16;
    half_t* d = dst + (size_t)(nb + n) * K + kb + kk;
    *(h16x8*)(d)     = *(const h16x8*)&Ts[n * LDSTR + kk];
    *(h16x8*)(d + 8) = *(const h16x8*)&Ts[n * LDSTR + kk + 8];
}

// ---------------------------------------------------------------------------
// K_FRONT (fused): one launch replacing memset + k_prep + k1.
//   blocks [0,320):     E = edge_ctx @ We + be  (We transposed inline in LDS)
//   blocks [320,1344):  Wc -> Wct (64x64 tile transpose, f16)
//   blocks [1344,1408): Wrel -> Wt (64-col zero-padded transpose)
//   blocks [1408,1472): zero `out` (replaces hipMemsetAsync dispatch)
// The GEMM blocks are the only consumers of the inline-transposed We tile, so
// there is no cross-block ordering hazard; transposes overlap with the GEMM.
// ---------------------------------------------------------------------------
__global__ __launch_bounds__(256) void k_front(
    const float* __restrict__ edge_ctx,
    const float* __restrict__ We,
    const float* __restrict__ be,
    const float* __restrict__ Wc,
    const float* __restrict__ Wrel,
    half_t* __restrict__ E,
    half_t* __restrict__ Wct,
    half_t* __restrict__ Wt,
    float* __restrict__ out)
{
    __shared__ __align__(16) char smem[2 * 64 * LDSTR * 2];  // 18432 B
    const int b = blockIdx.x;
    const int t = threadIdx.x;

    if (b < 320) {
        // ---- k1: E(1280x1024) = edge_ctx(1280x512) @ We(512x1024) + be ----
        half_t* As = (half_t*)smem;
        half_t* Bs = (half_t*)(smem + 64 * LDSTR * 2);

        const int m0 = (b % 20) * 64;
        const int n0 = (b / 20) * 64;
        const int wave = t >> 6, lane = t & 63;
        const int quad = lane >> 4, l16 = lane & 15;

        const int ar  = t >> 2;
        const int akb = (t & 3) * 16;
        const int kr  = t >> 4;           // B-transpose mapping
        const int nc  = (t & 15) * 4;

        f32x4 acc[4] = {};

        for (int k0 = 0; k0 < HID; k0 += 64) {
            // A: edge_ctx fp32 -> f16 rows (m-major, k-fast)
            {
                const float* src = edge_ctx + (size_t)(m0 + ar) * HID + k0 + akb;
#pragma unroll
                for (int i = 0; i < 2; ++i) {
                    float4 va = *(const float4*)(src + 8 * i);
                    float4 vb = *(const float4*)(src + 8 * i + 4);
                    h16x8 o;
                    o[0] = (half_t)va.x; o[1] = (half_t)va.y;
                    o[2] = (half_t)va.z; o[3] = (half_t)va.w;
                    o[4] = (half_t)vb.x; o[5] = (half_t)vb.y;
                    o[6] = (half_t)vb.z; o[7] = (half_t)vb.w;
                    *(h16x8*)&As[ar * LDSTR + akb + 8 * i] = o;
                }
            }
            // B: We fp32 (k-major) -> transposed f16 Bs[n][k], written directly
#pragma unroll
            for (int p = 0; p < 4; ++p) {
                float4 v = *(const float4*)(We + (size_t)(k0 + kr + 16 * p) * 1024 + n0 + nc);
                Bs[(nc + 0) * LDSTR + kr + 16 * p] = (half_t)v.x;
                Bs[(nc + 1) * LDSTR + kr + 16 * p] = (half_t)v.y;
                Bs[(nc + 2) * LDSTR + kr + 16 * p] = (half_t)v.z;
                Bs[(nc + 3) * LDSTR + kr + 16 * p] = (half_t)v.w;
            }
            __syncthreads();
#pragma unroll
            for (int s = 0; s < 2; ++s) {
                h16x8 a = *(const h16x8*)&As[(wave * 16 + l16) * LDSTR + s * 32 + quad * 8];
#pragma unroll
                for (int nt = 0; nt < 4; ++nt) {
                    h16x8 bb = *(const h16x8*)&Bs[(nt * 16 + l16) * LDSTR + s * 32 + quad * 8];
                    acc[nt] = __builtin_amdgcn_mfma_f32_16x16x32_f16(a, bb, acc[nt], 0, 0, 0);
                }
            }
            __syncthreads();
        }
#pragma unroll
        for (int nt = 0; nt < 4; ++nt) {
            int n = n0 + nt * 16 + l16;
            float bias = be[n];
#pragma unroll
            for (int r = 0; r < 4; ++r) {
                int m = m0 + wave * 16 + quad * 4 + r;
                E[(size_t)m * 1024 + n] = (half_t)(acc[nt][r] + bias);
            }
        }
    } else if (b < 1344) {
        const int c = b - 320;
        kt_tile(Wc, Wct, 1024, POOL, (c & 15) * 64, (c >> 4) * 64, (half_t*)smem);
    } else if (b < 1408) {
        float* Ls = (float*)smem;  // 13056 B needed <= 18432
        const int kb = (b - 1344) * 64;
        for (int f = t; f < 64 * NRC; f += 256)
            Ls[f] = Wrel[(size_t)kb * NRC + f];
        __syncthreads();
        const int n = t >> 2, kc = t & 3;
        h16x8 o0, o1;
#pragma unroll
        for (int e = 0; e < 8; ++e) {
            o0[e] = (n < NRC) ? (half_t)Ls[(kc * 16 + e) * NRC + n] : (half_t)0.0f;
            o1[e] = (n < NRC) ? (half_t)Ls[(kc * 16 + 8 + e) * NRC + n] : (half_t)0.0f;
        }
        half_t* d = Wt + (size_t)n * POOL + kb + kc * 16;
        *(h16x8*)(d)     = o0;
        *(h16x8*)(d + 8) = o1;
    } else {
        // zero the output tensor (exactly N_REL*NRC floats, 16B vectors)
        f32x4 z = {0.0f, 0.0f, 0.0f, 0.0f};
        f32x4* o4 = (f32x4*)out;
        const int total = (N_REL * NRC) / 4;
        for (int i = (b - 1408) * 256 + t; i < total; i += 64 * 256)
            o4[i] = z;
    }
}

// ---------------------------------------------------------------------------
// K2: 128x128 tile. z=0: H = E[:,:512]@Wc_top + b_cat ; z=1: T = E[:,512:]@Wc_bot
// ---------------------------------------------------------------------------
__global__ __launch_bounds__(256) void k2_ht(
    const half_t* __restrict__ E,
    const half_t* __restrict__ Wct,
    const float* __restrict__ bcat,
    half_t* __restrict__ Hws,
    half_t* __restrict__ Tws)
{
    __shared__ __align__(16) half_t As[128 * LDSTR];
    __shared__ __align__(16) half_t Bs[128 * LDSTR];

    const int z  = blockIdx.z;
    const int m0 = blockIdx.x * 128;
    const int n0 = blockIdx.y * 128;
    const int t = threadIdx.x;
    const int wave = t >> 6, lane = t & 63;
    const int quad = lane >> 4, l16 = lane & 15;
    const int wr = wave >> 1, wc = wave & 1;

    const int srow = t >> 3;
    const int sc   = (t & 7) * 8;

    f32x4 acc[4][4] = {};

    for (int k0 = 0; k0 < HID; k0 += 64) {
#pragma unroll
        for (int p = 0; p < 4; ++p) {
            int row = srow + 32 * p;
            *(h16x8*)&As[row * LDSTR + sc] =
                *(const h16x8*)(E + (size_t)(m0 + row) * 1024 + z * 512 + k0 + sc);
            *(h16x8*)&Bs[row * LDSTR + sc] =
                *(const h16x8*)(Wct + (size_t)(n0 + row) * 1024 + z * 512 + k0 + sc);
        }
        __syncthreads();
#pragma unroll
        for (int s = 0; s < 2; ++s) {
            h16x8 a[4], bfr[4];
#pragma unroll
            for (int i = 0; i < 4; ++i) {
                a[i]   = *(const h16x8*)&As[(wr * 64 + i * 16 + l16) * LDSTR + s * 32 + quad * 8];
                bfr[i] = *(const h16x8*)&Bs[(wc * 64 + i * 16 + l16) * LDSTR + s * 32 + quad * 8];
            }
#pragma unroll
            for (int ri = 0; ri < 4; ++ri)
#pragma unroll
                for (int ci = 0; ci < 4; ++ci)
                    acc[ri][ci] = __builtin_amdgcn_mfma_f32_16x16x32_f16(
                        a[ri], bfr[ci], acc[ri][ci], 0, 0, 0);
        }
        __syncthreads();
    }
    half_t* outp = z ? Tws : Hws;
#pragma unroll
    for (int ci = 0; ci < 4; ++ci) {
        int n = n0 + wc * 64 + ci * 16 + l16;
        float bias = z ? 0.0f : bcat[n];
#pragma unroll
        for (int ri = 0; ri < 4; ++ri) {
#pragma unroll
            for (int r = 0; r < 4; ++r) {
                int m = m0 + wr * 64 + ri * 16 + quad * 4 + r;
                outp[(size_t)m * POOL + n] = (half_t)(acc[ri][ci][r] + bias);
            }
        }
    }
}

// ---------------------------------------------------------------------------
// K3: out[r] = ((H[i_r]+T[j_r]) .* u[r]) @ W_rel + b_rel + freq[bias_idx]
// 64 rows/block, K-split x8 (512 per block), atomicAdd into zeroed out.
// 8 blocks/CU (LDS 18.4KB), 32 waves/CU for latency hiding of the union stream.
// Union is read exactly once -> non-temporal loads keep H/T/Wt resident in L2.
// ---------------------------------------------------------------------------
__global__ __launch_bounds__(256) void k3_main(
    const float* __restrict__ unionf,
    const half_t* __restrict__ Hws,
    const half_t* __restrict__ Tws,
    const half_t* __restrict__ Wt,
    const float* __restrict__ brel,
    const float* __restrict__ freq,
    const int* __restrict__ pair_idx,
    const int* __restrict__ obj_preds,
    float* __restrict__ out)
{
    __shared__ __align__(16) half_t As[64 * LDSTR];
    __shared__ __align__(16) half_t Bs[64 * LDSTR];

    const int R0 = blockIdx.x * 64;
    const int kbase = blockIdx.y * (POOL / KSPLIT);
    const int t = threadIdx.x;
    const int wave = t >> 6, lane = t & 63;
    const int quad = lane >> 4, l16 = lane & 15;

    const int ar  = t >> 2;
    const int akb = (t & 3) * 16;

    const int2 pr = *(const int2*)(pair_idx + 2 * (R0 + ar));
    const half_t* Hrow = Hws + (size_t)pr.x * POOL;
    const half_t* Trow = Tws + (size_t)pr.y * POOL;
    const float*  urow = unionf + (size_t)(R0 + ar) * POOL;

    f32x4 acc[4] = {};

    for (int k0 = kbase; k0 < kbase + POOL / KSPLIT; k0 += 64) {
#pragma unroll
        for (int i = 0; i < 2; ++i) {
            h16x8 hv = *(const h16x8*)(Hrow + k0 + akb + 8 * i);
            h16x8 tv = *(const h16x8*)(Trow + k0 + akb + 8 * i);
            f32x4 ua = __builtin_nontemporal_load((const f32x4*)(urow + k0 + akb + 8 * i));
            f32x4 ub = __builtin_nontemporal_load((const f32x4*)(urow + k0 + akb + 8 * i + 4));
            h16x8 o;
            o[0] = (half_t)(((float)hv[0] + (float)tv[0]) * ua[0]);
            o[1] = (half_t)(((float)hv[1] + (float)tv[1]) * ua[1]);
            o[2] = (half_t)(((float)hv[2] + (float)tv[2]) * ua[2]);
            o[3] = (half_t)(((float)hv[3] + (float)tv[3]) * ua[3]);
            o[4] = (half_t)(((float)hv[4] + (float)tv[4]) * ub[0]);
            o[5] = (half_t)(((float)hv[5] + (float)tv[5]) * ub[1]);
            o[6] = (half_t)(((float)hv[6] + (float)tv[6]) * ub[2]);
            o[7] = (half_t)(((float)hv[7] + (float)tv[7]) * ub[3]);
            *(h16x8*)&As[ar * LDSTR + akb + 8 * i] = o;
        }
        {
            const half_t* src = Wt + (size_t)ar * POOL + k0 + akb;
            *(h16x8*)&Bs[ar * LDSTR + akb]     = *(const h16x8*)(src);
            *(h16x8*)&Bs[ar * LDSTR + akb + 8] = *(const h16x8*)(src + 8);
        }
        __syncthreads();
#pragma unroll
        for (int s = 0; s < 2; ++s) {
            h16x8 a = *(const h16x8*)&As[(wave * 16 + l16) * LDSTR + s * 32 + quad * 8];
#pragma unroll
            for (int nt = 0; nt < 4; ++nt) {
                h16x8 bb = *(const h16x8*)&Bs[(nt * 16 + l16) * LDSTR + s * 32 + quad * 8];
                acc[nt] = __builtin_amdgcn_mfma_f32_16x16x32_f16(a, bb, acc[nt], 0, 0, 0);
            }
        }
        __syncthreads();
    }
    const bool first = (blockIdx.y == 0);
#pragma unroll
    for (int r = 0; r < 4; ++r) {
        int grow = R0 + wave * 16 + quad * 4 + r;
        const float* frow = nullptr;
        if (first) {
            int2 p = *(const int2*)(pair_idx + 2 * grow);
            frow = freq + (size_t)(obj_preds[p.x] * NOC + obj_preds[p.y]) * NRC;
        }
#pragma unroll
        for (int nt = 0; nt < 4; ++nt) {
            int n = nt * 16 + l16;
            if (n < NRC) {
                float v = acc[nt][r];
                if (first) v += brel[n] + frow[n];
                atomicAdd(&out[(size_t)grow * NRC + n], v);
            }
        }
    }
}

// ---------------------------------------------------------------------------
extern "C" void kernel_launch(void* const* d_in, const int* in_sizes, int n_in,
                              void* d_out, int out_size, void* d_ws, size_t ws_size,
                              hipStream_t stream) {
    const float* edge_ctx  = (const float*)d_in[0];
    const float* unionf    = (const float*)d_in[1];
    const float* We        = (const float*)d_in[2];
    const float* be        = (const float*)d_in[3];
    const float* Wc        = (const float*)d_in[4];
    const float* bcat      = (const float*)d_in[5];
    const float* Wrel      = (const float*)d_in[6];
    const float* brel      = (const float*)d_in[7];
    const float* freq      = (const float*)d_in[8];
    const int*   pair_idx  = (const int*)d_in[9];
    const int*   obj_preds = (const int*)d_in[10];
    float* out = (float*)d_out;

    char* ws = (char*)d_ws;
    half_t* E   = (half_t*)(ws);
    half_t* H   = (half_t*)(ws + 2621440);
    half_t* T   = (half_t*)(ws + 13107200);
    half_t* Wt  = (half_t*)(ws + 23592960);
    half_t* Wct = (half_t*)(ws + 24117248);

    k_front<<<1472, 256, 0, stream>>>(edge_ctx, We, be, Wc, Wrel, E, Wct, Wt, out);
    k2_ht<<<dim3(N_OBJ / 128, POOL / 128, 2), 256, 0, stream>>>(E, Wct, bcat, H, T);
    k3_main<<<dim3(N_REL / 64, KSPLIT), 256, 0, stream>>>(unionf, H, T, Wt, brel, freq,
                                                          pair_idx, obj_preds, out);
}